// Round 1
// baseline (4351.937 us; speedup 1.0000x reference)
//
#include <hip/hip_runtime.h>
#include <cstdint>
#include <cstddef>

// Problem constants (from setup_inputs)
#define N_NEU   4096
#define N_IN    1024
#define B_SZ    8
#define T_STEPS 500
// ws layout (floats):
//   v[32768] | ref[32768] | h0..h3[4*32768] | g0..g3[4*32768]  -> 327680 floats
// then (ints): lists[2][8][4096] = 65536 | cnts[(T+1)*8*16] = 64128
#define ST_V    0
#define ST_REF  32768
#define ST_H    65536
#define ST_G    (65536 + 4*32768)
#define ST_TOT  327680

__global__ __launch_bounds__(256) void snn_init(float* __restrict__ st, int* __restrict__ cnts) {
    int idx = blockIdx.x * 256 + threadIdx.x;   // 128 blocks -> 32768 threads
    st[ST_V + idx]   = -70.0f;   // v0 = E_L
    st[ST_REF + idx] = 0.0f;
#pragma unroll
    for (int q = 0; q < 4; ++q) {
        st[ST_H + q*32768 + idx] = 0.0f;
        st[ST_G + q*32768 + idx] = 0.0f;
    }
    if (idx < 128) cnts[idx] = 0;   // step-0 spike counts (s_prev = 0)
}

__global__ __launch_bounds__(256) void snn_step(
    const float* __restrict__ inspk,   // (B,T,NI)
    const float* __restrict__ W,       // (N,N) row j = presyn
    const float* __restrict__ Wff,     // (NI,N)
    const float* __restrict__ sf,      // (2,2) [pre][post]
    const float* __restrict__ sfff,    // (1,2)
    const int*   __restrict__ ci,      // (N)
    float*       __restrict__ out,     // (B,T,N)
    float*       __restrict__ st,
    int*         __restrict__ lists,
    int*         __restrict__ cnts,
    int t)
{
#pragma clang fp contract(off)
    const int tid   = threadIdx.x;
    const int b     = blockIdx.x >> 4;
    const int chunk = blockIdx.x & 15;
    const int i     = (chunk << 8) + tid;       // postsyn neuron index in [0,4096)
    const int c     = ci[i];                    // my cell type

    const float s_exc = sf[c];          // scaling_factors[0][c]
    const float s_inh = sf[2 + c];      // scaling_factors[1][c]
    const float s_ff  = sfff[c];        // scaling_factors_FF[0][c]

    // ---- recurrent sparse accumulate, exact presyn-index order ----
    float exc = 0.0f, inh = 0.0f;
    {
        const int* cbase = cnts + t * 128 + b * 16;
        const int* lbase = lists + (t & 1) * 32768 + b * 4096;
        const float* Wi = W + i;
        for (int cc = 0; cc < 16; ++cc) {
            const int cnt = cbase[cc];
            const int* lst = lbase + (cc << 8);
            for (int k = 0; k < cnt; ++k) {
                const int e = lst[k];                       // (j<<1)|type, j ascending
                const float w = Wi[(size_t)(e >> 1) << 12];
                if (e & 1) inh += w * s_inh;                // product rounded per-element,
                else       exc += w * s_exc;                // matching W_eff = w*sf then add
            }
        }
    }

    // ---- feedforward sparse accumulate (ballot-compaction, ascending k) ----
    __shared__ int s_ffl[1024];
    __shared__ int s_w[4];
    float ffd = 0.0f;
    {
        const float* isp = inspk + ((size_t)b * T_STEPS + t) * N_IN;
        int total = 0;
        for (int p = 0; p < 4; ++p) {
            const int k = (p << 8) + tid;
            const bool on = isp[k] > 0.5f;                  // spikes are exactly 0/1
            const unsigned long long m = __ballot(on);
            const int lane = tid & 63, wv = tid >> 6;
            if (lane == 0) s_w[wv] = __popcll(m);
            __syncthreads();
            int off = total;
            for (int q = 0; q < wv; ++q) off += s_w[q];
            if (on) s_ffl[off + __popcll(m & ((1ULL << lane) - 1ULL))] = k;
            total += s_w[0] + s_w[1] + s_w[2] + s_w[3];
            __syncthreads();
        }
        const float* Wffi = Wff + i;
        for (int k = 0; k < total; ++k) {
            const float w = Wffi[(size_t)s_ffl[k] << 12];
            ffd += w * s_ff;
        }
    }

    // ---- neuron update (mirror reference fp ops exactly) ----
    const int s_idx = b * N_NEU + i;
    float v  = st[ST_V + s_idx];
    float rf = st[ST_REF + s_idx];
    float h0 = st[ST_H + 0*32768 + s_idx];
    float h1 = st[ST_H + 1*32768 + s_idx];
    float h2 = st[ST_H + 2*32768 + s_idx];
    float h3 = st[ST_H + 3*32768 + s_idx];
    float g0 = st[ST_G + 0*32768 + s_idx];
    float g1 = st[ST_G + 1*32768 + s_idx];
    float g2 = st[ST_G + 2*32768 + s_idx];
    float g3 = st[ST_G + 3*32768 + s_idx];

    // A_RISE = exp(-DT/TAU_RISE), TAU_RISE={0.5,2,0.5,0.5}; A_DECAY for {2,100,5,2}
    const float aR0 = expf(-0.1f / 0.5f);
    const float aR1 = expf(-0.1f / 2.0f);
    const float aD0 = expf(-0.1f / 2.0f);
    const float aD1 = expf(-0.1f / 100.0f);
    const float aD2 = expf(-0.1f / 5.0f);

    // drive channels: [exc*1, exc*0.5, inh*1, ff*1]  (G_BAR = {1,0.5,1,1})
    const float d0 = exc;
    const float d1 = 0.5f * exc;
    const float d2 = inh;
    const float d3 = ffd;

    h0 = fmaf(h0, aR0, d0);
    h1 = fmaf(h1, aR1, d1);
    h2 = fmaf(h2, aR0, d2);
    h3 = fmaf(h3, aR0, d3);
    g0 = fmaf(g0, aD0, (1.0f - aD0) * h0);
    g1 = fmaf(g1, aD1, (1.0f - aD1) * h1);
    g2 = fmaf(g2, aD2, (1.0f - aD2) * h2);
    g3 = fmaf(g3, aD0, (1.0f - aD0) * h3);

    const float p0 = g0 * (0.0f - v);
    const float p1 = g1 * (0.0f - v);
    const float p2 = g2 * (-80.0f - v);
    const float p3 = g3 * (0.0f - v);
    const float Isyn = ((p0 + p1) + p2) + p3;

    const float kmem = c ? (0.1f / 10.0f) : (0.1f / 20.0f);  // DT/tau_mem
    float vn = fmaf(kmem, (-70.0f - v) + Isyn / 10.0f, v);
    const bool refr = rf > 0.0f;
    if (refr) vn = -65.0f;                                    // u_reset
    const float sn = (!refr && (vn > -50.0f)) ? 1.0f : 0.0f;  // theta = -50
    const bool spk = sn > 0.5f;
    const float vpost = spk ? -65.0f : vn;
    const float rsteps = c ? 10.0f : 20.0f;
    const float rnew = spk ? rsteps : fmaxf(rf - 1.0f, 0.0f);

    st[ST_V + s_idx]   = vpost;
    st[ST_REF + s_idx] = rnew;
    st[ST_H + 0*32768 + s_idx] = h0;
    st[ST_H + 1*32768 + s_idx] = h1;
    st[ST_H + 2*32768 + s_idx] = h2;
    st[ST_H + 3*32768 + s_idx] = h3;
    st[ST_G + 0*32768 + s_idx] = g0;
    st[ST_G + 1*32768 + s_idx] = g1;
    st[ST_G + 2*32768 + s_idx] = g2;
    st[ST_G + 3*32768 + s_idx] = g3;
    out[((size_t)b * T_STEPS + t) * N_NEU + i] = sn;

    // ---- build next step's spike list (deterministic, ascending j within chunk) ----
    {
        const unsigned long long m = __ballot(spk);
        const int lane = tid & 63, wv = tid >> 6;
        if (lane == 0) s_w[wv] = __popcll(m);
        __syncthreads();
        int off = 0;
        for (int q = 0; q < wv; ++q) off += s_w[q];
        int* olist = lists + ((t + 1) & 1) * 32768 + b * 4096 + (chunk << 8);
        if (spk) olist[off + __popcll(m & ((1ULL << lane) - 1ULL))] = (i << 1) | c;
        if (tid == 0) cnts[(t + 1) * 128 + b * 16 + chunk] =
            s_w[0] + s_w[1] + s_w[2] + s_w[3];
    }
}

extern "C" void kernel_launch(void* const* d_in, const int* in_sizes, int n_in,
                              void* d_out, int out_size, void* d_ws, size_t ws_size,
                              hipStream_t stream) {
    const float* inspk = (const float*)d_in[0];
    const float* W     = (const float*)d_in[1];
    const float* Wff   = (const float*)d_in[2];
    const float* sf    = (const float*)d_in[3];
    const float* sfff  = (const float*)d_in[4];
    const int*   ci    = (const int*)d_in[5];
    // d_in[6] = cell_type_indices_FF (all zeros, folded into sfff indexing)

    float* out   = (float*)d_out;
    float* st    = (float*)d_ws;
    int*   lists = (int*)((char*)d_ws + (size_t)ST_TOT * 4);
    int*   cnts  = lists + 2 * B_SZ * N_NEU;

    snn_init<<<128, 256, 0, stream>>>(st, cnts);
    for (int t = 0; t < T_STEPS; ++t)
        snn_step<<<128, 256, 0, stream>>>(inspk, W, Wff, sf, sfff, ci,
                                          out, st, lists, cnts, t);
}

// Round 2
// 3037.107 us; speedup vs baseline: 1.4329x; 1.4329x over previous
//
#include <hip/hip_runtime.h>
#include <cstdint>
#include <cstddef>

// Problem constants
#define N_NEU   4096
#define N_IN    1024
#define B_SZ    8
#define T_STEPS 500
// ws layout:
//   floats: v[32768] | ref[32768] | h0..h3[4*32768] | g0..g3[4*32768] = 327680 floats
//   u64 ffmask[B*T*16] = 64000 words  (bitmask of input spikes per (b,t))
//   u64 recmask[2][2][8][64] = 2048 words (double-buffered exc/inh spike masks)
#define ST_V    0
#define ST_REF  32768
#define ST_H    65536
#define ST_G    (65536 + 4*32768)
#define ST_TOT  327680
#define FF_WORDS (B_SZ * T_STEPS * 16)

__global__ __launch_bounds__(256) void snn_init(float* __restrict__ st,
                                                unsigned long long* __restrict__ recmask) {
    int idx = blockIdx.x * 256 + threadIdx.x;   // 128 blocks -> 32768 threads
    st[ST_V + idx]   = -70.0f;   // v0 = E_L
    st[ST_REF + idx] = 0.0f;
#pragma unroll
    for (int q = 0; q < 4; ++q) {
        st[ST_H + q*32768 + idx] = 0.0f;
        st[ST_G + q*32768 + idx] = 0.0f;
    }
    if (idx < 2048) recmask[idx] = 0ULL;  // no spikes at t=0
}

// input spikes (B,T,NI) -> bitmask words, 64 elems per word, ascending order
__global__ __launch_bounds__(256) void snn_ffmask(const float* __restrict__ inspk,
                                                  unsigned long long* __restrict__ ffmask) {
    int gid  = blockIdx.x * 256 + threadIdx.x;
    int wid  = gid >> 6, lane = gid & 63;
    int nw   = (gridDim.x * 256) >> 6;
    for (int w = wid; w < FF_WORDS; w += nw) {
        float v = inspk[(size_t)w * 64 + lane];
        unsigned long long m = __ballot(v > 0.5f);
        if (lane == 0) ffmask[w] = m;
    }
}

// extract set-bit indices (bit b of lane l's word -> index l*64+b) into lds,
// globally ascending. Returns total count. One wave (64 threads).
__device__ __forceinline__ int extract_bits(unsigned long long m, int* lds) {
    const int lane = threadIdx.x;
    int pc  = __popcll(m);
    int sum = pc;
#pragma unroll
    for (int d = 1; d < 64; d <<= 1) {
        int o = __shfl_up(sum, d, 64);
        if (lane >= d) sum += o;
    }
    int off   = sum - pc;           // exclusive prefix
    int total = __shfl(sum, 63, 64);
    int base  = lane << 6;
    while (m) {
        int b = __builtin_ctzll(m);
        lds[off++] = base + b;
        m &= m - 1ULL;
    }
    return total;
}

// sum of round(w*s) over listed rows, ascending order, 4-wide load pipelining
__device__ __forceinline__ float gather_rows(const int* __restrict__ lst, int n,
                                             const float* __restrict__ base, float s) {
#pragma clang fp contract(off)
    float acc = 0.0f;
    int k = 0;
    for (; k + 4 <= n; k += 4) {
        int j0 = lst[k], j1 = lst[k+1], j2 = lst[k+2], j3 = lst[k+3];
        float w0 = base[(size_t)j0 << 12];
        float w1 = base[(size_t)j1 << 12];
        float w2 = base[(size_t)j2 << 12];
        float w3 = base[(size_t)j3 << 12];
        acc += w0 * s; acc += w1 * s; acc += w2 * s; acc += w3 * s;
    }
    for (; k < n; ++k) {
        float w = base[(size_t)lst[k] << 12];
        acc += w * s;
    }
    return acc;
}

__global__ __launch_bounds__(64) void snn_step(
    const float* __restrict__ W,       // (N,N) row j = presyn
    const float* __restrict__ Wff,     // (NI,N)
    const float* __restrict__ sf,      // (2,2)
    const float* __restrict__ sfff,    // (1,2)
    const int*   __restrict__ ci,      // (N)
    float*       __restrict__ out,     // (B,T,N)
    float*       __restrict__ st,
    const unsigned long long* __restrict__ ffmask,
    unsigned long long* __restrict__ recmask,
    int t)
{
#pragma clang fp contract(off)
    const int lane  = threadIdx.x;
    const int b     = blockIdx.x >> 6;
    const int chunk = blockIdx.x & 63;          // 64-neuron slice; same chunk, all b -> same XCD
    const int i     = (chunk << 6) + lane;
    const int c     = ci[i];

    const float s_exc = sf[c];
    const float s_inh = sf[2 + c];
    const float s_ff  = sfff[c];

    __shared__ int lds_exc[4096];
    __shared__ int lds_inh[4096];
    __shared__ int lds_ff[1024];

    // ---- build ascending index lists from bitmasks ----
    const int buf = t & 1;
    const unsigned long long me_w = recmask[((buf*2 + 0)*8 + b)*64 + lane];
    const unsigned long long mi_w = recmask[((buf*2 + 1)*8 + b)*64 + lane];
    const unsigned long long mf_w = (lane < 16) ? ffmask[((size_t)b * T_STEPS + t) * 16 + lane] : 0ULL;
    const int n_exc = extract_bits(me_w, lds_exc);
    const int n_inh = extract_bits(mi_w, lds_inh);
    const int n_ff  = extract_bits(mf_w, lds_ff);
    __threadfence_block();

    // ---- sparse gathers (exc/inh are separate accumulators in the reference too) ----
    const float exc = gather_rows(lds_exc, n_exc, W + i, s_exc);
    const float inh = gather_rows(lds_inh, n_inh, W + i, s_inh);
    const float ffd = gather_rows(lds_ff,  n_ff,  Wff + i, s_ff);

    // ---- neuron update (identical fp op sequence to R1: bit-exact) ----
    const int s_idx = b * N_NEU + i;
    float v  = st[ST_V + s_idx];
    float rf = st[ST_REF + s_idx];
    float h0 = st[ST_H + 0*32768 + s_idx];
    float h1 = st[ST_H + 1*32768 + s_idx];
    float h2 = st[ST_H + 2*32768 + s_idx];
    float h3 = st[ST_H + 3*32768 + s_idx];
    float g0 = st[ST_G + 0*32768 + s_idx];
    float g1 = st[ST_G + 1*32768 + s_idx];
    float g2 = st[ST_G + 2*32768 + s_idx];
    float g3 = st[ST_G + 3*32768 + s_idx];

    const float aR0 = expf(-0.1f / 0.5f);
    const float aR1 = expf(-0.1f / 2.0f);
    const float aD0 = expf(-0.1f / 2.0f);
    const float aD1 = expf(-0.1f / 100.0f);
    const float aD2 = expf(-0.1f / 5.0f);

    const float d0 = exc;
    const float d1 = 0.5f * exc;
    const float d2 = inh;
    const float d3 = ffd;

    h0 = fmaf(h0, aR0, d0);
    h1 = fmaf(h1, aR1, d1);
    h2 = fmaf(h2, aR0, d2);
    h3 = fmaf(h3, aR0, d3);
    g0 = fmaf(g0, aD0, (1.0f - aD0) * h0);
    g1 = fmaf(g1, aD1, (1.0f - aD1) * h1);
    g2 = fmaf(g2, aD2, (1.0f - aD2) * h2);
    g3 = fmaf(g3, aD0, (1.0f - aD0) * h3);

    const float p0 = g0 * (0.0f - v);
    const float p1 = g1 * (0.0f - v);
    const float p2 = g2 * (-80.0f - v);
    const float p3 = g3 * (0.0f - v);
    const float Isyn = ((p0 + p1) + p2) + p3;

    const float kmem = c ? (0.1f / 10.0f) : (0.1f / 20.0f);
    float vn = fmaf(kmem, (-70.0f - v) + Isyn / 10.0f, v);
    const bool refr = rf > 0.0f;
    if (refr) vn = -65.0f;
    const float sn = (!refr && (vn > -50.0f)) ? 1.0f : 0.0f;
    const bool spk = sn > 0.5f;
    const float vpost = spk ? -65.0f : vn;
    const float rsteps = c ? 10.0f : 20.0f;
    const float rnew = spk ? rsteps : fmaxf(rf - 1.0f, 0.0f);

    st[ST_V + s_idx]   = vpost;
    st[ST_REF + s_idx] = rnew;
    st[ST_H + 0*32768 + s_idx] = h0;
    st[ST_H + 1*32768 + s_idx] = h1;
    st[ST_H + 2*32768 + s_idx] = h2;
    st[ST_H + 3*32768 + s_idx] = h3;
    st[ST_G + 0*32768 + s_idx] = g0;
    st[ST_G + 1*32768 + s_idx] = g1;
    st[ST_G + 2*32768 + s_idx] = g2;
    st[ST_G + 3*32768 + s_idx] = g3;
    out[((size_t)b * T_STEPS + t) * N_NEU + i] = sn;

    // ---- next step's spike masks: one ballot per type, one word per block ----
    const unsigned long long new_e = __ballot(spk && (c == 0));
    const unsigned long long new_i = __ballot(spk && (c == 1));
    if (lane == 0) {
        const int nbuf = (t + 1) & 1;
        recmask[((nbuf*2 + 0)*8 + b)*64 + chunk] = new_e;
        recmask[((nbuf*2 + 1)*8 + b)*64 + chunk] = new_i;
    }
}

extern "C" void kernel_launch(void* const* d_in, const int* in_sizes, int n_in,
                              void* d_out, int out_size, void* d_ws, size_t ws_size,
                              hipStream_t stream) {
    const float* inspk = (const float*)d_in[0];
    const float* W     = (const float*)d_in[1];
    const float* Wff   = (const float*)d_in[2];
    const float* sf    = (const float*)d_in[3];
    const float* sfff  = (const float*)d_in[4];
    const int*   ci    = (const int*)d_in[5];

    float* out   = (float*)d_out;
    float* st    = (float*)d_ws;
    unsigned long long* ffmask  = (unsigned long long*)((char*)d_ws + (size_t)ST_TOT * 4);
    unsigned long long* recmask = ffmask + FF_WORDS;

    snn_init<<<128, 256, 0, stream>>>(st, recmask);
    snn_ffmask<<<1000, 256, 0, stream>>>(inspk, ffmask);
    for (int t = 0; t < T_STEPS; ++t)
        snn_step<<<512, 64, 0, stream>>>(W, Wff, sf, sfff, ci,
                                         out, st, ffmask, recmask, t);
}